// Round 15
// baseline (118.325 us; speedup 1.0000x reference)
//
#include <hip/hip_runtime.h>
#include <math.h>

#define BB 8
#define NN 500
#define DDIM 256
#define HH 480
#define WW 640
#define HWSZ (HH*WW)        // 307200
#define BHW (BB*HWSZ)       // 2457600
#define NBLK 4800           // 8x8 blocks per image
#define NOVF 3392           // overflow candidate slots per image
#define NLIST (BB*NN*BB)    // 32000 deterministic list slots
#define NBCE2 512           // bce streaming blocks (inside k_front)
#define NCORR 125           // ceil(32000/256)
#define NDM 66              // dist-mfma blocks
#define NLAST (NDM + 512 + NCORR)   // 703 blocks in k_last

// partial-sum slot map (doubles at ws start)
#define PD_DIST  0          // 66 used
#define PD_MS    512        // 512
#define PD_MC    1024       // 512
#define PD_BCE   1536       // 512
#define PD_CORR  2560       // 125
#define PD_TOTAL 2688

typedef __attribute__((ext_vector_type(8))) short short8;
typedef __attribute__((ext_vector_type(4))) float f32x4;

// ---------------- helpers ----------------

static __device__ __forceinline__ float wredmaxf(float v) {
  #pragma unroll
  for (int o = 1; o < 64; o <<= 1) v = fmaxf(v, __shfl_xor(v, o, 64));
  return v;
}

static __device__ __forceinline__ double blockRedSum256(double v) {
  __shared__ double sp[4];
  __syncthreads();
  #pragma unroll
  for (int o = 32; o > 0; o >>= 1) v += __shfl_down(v, o, 64);
  int lane = threadIdx.x & 63, wid = threadIdx.x >> 6;
  if (lane == 0) sp[wid] = v;
  __syncthreads();
  double r = 0.0;
  if (threadIdx.x == 0) r = sp[0] + sp[1] + sp[2] + sp[3];
  return r;
}

static __device__ __forceinline__ unsigned short f2bf(float f) {
  unsigned u = __float_as_uint(f);
  return (unsigned short)((u + 0x7FFFu + ((u >> 16) & 1u)) >> 16);   // RNE
}

static __device__ __forceinline__ float bilin(const float* __restrict__ img, float px, float py) {
  float x = fminf(fmaxf(px, 0.0f), 639.0f);
  float y = fminf(fmaxf(py, 0.0f), 479.0f);
  float x0 = floorf(x), y0 = floorf(y);
  float x1 = fminf(x0 + 1.0f, 639.0f);
  float y1 = fminf(y0 + 1.0f, 479.0f);
  float wx = x - x0, wy = y - y0;
  int x0i = (int)x0, x1i = (int)x1, y0i = (int)y0, y1i = (int)y1;
  float v00 = img[y0i*WW + x0i], v01 = img[y0i*WW + x1i];
  float v10 = img[y1i*WW + x0i], v11 = img[y1i*WW + x1i];
  return v00*(1.0f-wx)*(1.0f-wy) + v01*wx*(1.0f-wy) + v10*(1.0f-wx)*wy + v11*wx*wy;
}

// world point from pixel (px,py) in image bimg; replicates reference op order
static __device__ void src_compute(float px, float py, const float* __restrict__ dep,
                                   const float* __restrict__ poses, const float* __restrict__ Km,
                                   int bimg, float* Xw, float* dout) {
  float d = bilin(dep, px, py);
  const float* Kb = Km + bimg*9;
  double a00=Kb[0],a01=Kb[1],a02=Kb[2],a10=Kb[3],a11=Kb[4],a12=Kb[5],a20=Kb[6],a21=Kb[7],a22=Kb[8];
  double det = a00*(a11*a22-a12*a21) - a01*(a10*a22-a12*a20) + a02*(a10*a21-a11*a20);
  double id = 1.0/det;
  float i00=(float)((a11*a22-a12*a21)*id), i01=(float)((a02*a21-a01*a22)*id), i02=(float)((a01*a12-a02*a11)*id);
  float i10=(float)((a12*a20-a10*a22)*id), i11=(float)((a00*a22-a02*a20)*id), i12=(float)((a02*a10-a00*a12)*id);
  float i20=(float)((a10*a21-a11*a20)*id), i21=(float)((a01*a20-a00*a21)*id), i22=(float)((a00*a11-a01*a10)*id);
  float c0 = i00*px + i01*py + i02;
  float c1 = i10*px + i11*py + i12;
  float c2 = i20*px + i21*py + i22;
  float X0 = d*c0, X1 = d*c1, X2 = d*c2;
  const float* P = poses + bimg*16;
  Xw[0] = (P[0]*X0 + P[1]*X1 + P[2]*X2)  + P[3];
  Xw[1] = (P[4]*X0 + P[5]*X1 + P[6]*X2)  + P[7];
  Xw[2] = (P[8]*X0 + P[9]*X1 + P[10]*X2) + P[11];
  *dout = d;
}

static __device__ void project_to(const float* __restrict__ poses, const float* __restrict__ Km,
                                  int j, const float* Xw, float dsrc,
                                  float* pnx, float* pny, bool* invis) {
  const float* P = poses + j*16;
  float d0 = Xw[0]-P[3], d1 = Xw[1]-P[7], d2 = Xw[2]-P[11];
  float Xj0 = P[0]*d0 + P[4]*d1 + P[8]*d2;
  float Xj1 = P[1]*d0 + P[5]*d1 + P[9]*d2;
  float Xj2 = P[2]*d0 + P[6]*d1 + P[10]*d2;
  const float* Kb = Km + j*9;
  float u = Kb[0]*Xj0 + Kb[1]*Xj1 + Kb[2]*Xj2;
  float v = Kb[3]*Xj0 + Kb[4]*Xj1 + Kb[5]*Xj2;
  float z = Kb[6]*Xj0 + Kb[7]*Xj1 + Kb[8]*Xj2;
  float zs = (fabsf(z) < 1e-6f) ? 1e-6f : z;
  float pu = u/zs, pv = v/zs;
  float nx = 2.0f*pu/639.0f - 1.0f;
  float ny = 2.0f*pv/479.0f - 1.0f;
  *pnx = nx; *pny = ny;
  *invis = (z <= 1e-6f) || (fabsf(nx) > 1.0f) || (fabsf(ny) > 1.0f) || (dsrc <= 0.0f);
}

// ---------------- kernels ----------------

// k_front: [0,2400) FULLY FUSED gray->sobel->separable-GFTT->separable-5x5-NMS->
//   candidate extraction per 32x32 tile (resp never leaves LDS; + ws inits on bid<20);
// [2400,3400) desc normalize (4 rows/block, wave-per-row); [3400,3416) match src+proj;
// [3416,3928) streaming BCE (t=false assumption).
__global__ __launch_bounds__(256) void k_front(const float* __restrict__ imgs,
                                               float* __restrict__ cv, int* __restrict__ ci,
                                               float* __restrict__ cvo, int* __restrict__ cio,
                                               int* __restrict__ ovf, int* __restrict__ list,
                                               unsigned int* __restrict__ dnb_u, int* __restrict__ done,
                                               const float* __restrict__ desc, float* __restrict__ dn,
                                               unsigned short* __restrict__ dnb,
                                               const float* __restrict__ points, const float* __restrict__ depths,
                                               const float* __restrict__ poses, const float* __restrict__ Km,
                                               float* __restrict__ psrc, float* __restrict__ pdst,
                                               int* __restrict__ minv,
                                               const float* __restrict__ pn, double* __restrict__ pd,
                                               float* __restrict__ target) {
  __shared__ float smem[8064];
  __shared__ float Gw[7];
  int bid = blockIdx.x, tid = threadIdx.x;
  if (bid < 2400) {
    // LDS phase layout (aliased):
    float* sgxy = smem;              // [42][42][2] = 3528          phases 2-3
    float* gray = smem + 3528;       // [44][45] = 1980             phases 1-2 (dead after sobel)
    float* hxx  = smem + 3528;       // [42][36] = 1512  aliases gray   phases 3-4
    float* hyy  = hxx + 1512;
    float* hxy  = hyy + 1512;        // ends at 3528+4536 = 8064
    float* s    = smem;              // [36][37] = 1332  aliases sgxy  phases 4-6
    float* hm   = smem + 1332;       // [36][32] = 1152
    float* c32  = smem + 2484;       // [32][32] = 1024
    int b = bid / 300, r = bid % 300;
    int byi = r / 20, bxi = r % 20;
    int bx = bxi*32, by = byi*32;
    if (bid < 20) {
      int g = bid*256 + tid;                 // 0..5119
      if (g == 0) *done = 0;
      for (int e = g; e < BB*64; e += 20*256) ovf[e] = 0;
      for (int e = g; e < NLIST; e += 20*256) list[e] = -1;
      for (int e = g; e < 12288; e += 20*256) {     // zero bf16 pad rows 500..511 per image
        int bi = e / 1536, rr2 = e % 1536;
        dnb_u[(bi*512 + 500)*128 + rr2] = 0u;
      }
    }
    if (tid < 7) {
      double g[7]; double sm = 0.0;
      for (int q = 0; q < 7; q++) { double rr2 = (double)(q-3); g[q] = exp(-(rr2*rr2)/2.0); sm += g[q]; }
      Gw[tid] = (float)(g[tid]/sm);
    }
    const float* ib = imgs + (size_t)b*3*HWSZ;
    // phase 1: gray 44x44 (halo 6)
    for (int e = tid; e < 44*44; e += 256) {
      int ly = e/44, lx = e%44;
      int X = bx - 6 + lx, Y = by - 6 + ly;
      float v = 0.f;
      if (X>=0 && X<WW && Y>=0 && Y<HH) {
        int p = Y*WW + X;
        v = 0.299f*ib[p] + 0.587f*ib[HWSZ+p] + 0.114f*ib[2*HWSZ+p];
      }
      gray[ly*45+lx] = v;
    }
    __syncthreads();
    // phase 2: sobel 42x42 (halo 5); zero outside image (conv zero-pad semantics)
    const float kxw[3][3] = {{-0.125f,0.f,0.125f},{-0.25f,0.f,0.25f},{-0.125f,0.f,0.125f}};
    for (int e = tid; e < 42*42; e += 256) {
      int ly = e/42, lx = e%42;
      int X = bx - 5 + lx, Y = by - 5 + ly;
      float sx = 0.f, sy = 0.f;
      #pragma unroll
      for (int i = 0; i < 3; i++)
        #pragma unroll
        for (int j = 0; j < 3; j++) {
          float v = gray[(ly+i)*45 + (lx+j)];
          sx += kxw[i][j]*v;
          sy += kxw[j][i]*v;
        }
      bool in = (X>=0 && X<WW && Y>=0 && Y<HH);
      sgxy[e*2]   = in ? sx : 0.f;
      sgxy[e*2+1] = in ? sy : 0.f;
    }
    __syncthreads();
    // phase 3: gauss H-pass [42 rows][36 cols] (col c -> x = bx-2+c)
    for (int e = tid; e < 42*36; e += 256) {
      int rr2 = e/36, c = e%36;
      int base = (rr2*42 + c)*2;
      float axx = 0.f, ayy = 0.f, axy = 0.f;
      #pragma unroll
      for (int j = 0; j < 7; j++) {
        float a = sgxy[base + j*2];
        float cc = sgxy[base + j*2 + 1];
        float Gj = Gw[j];
        axx += Gj*(a*a); ayy += Gj*(cc*cc); axy += Gj*(a*cc);
      }
      hxx[e] = axx; hyy[e] = ayy; hxy[e] = axy;
    }
    __syncthreads();
    // phase 4: gauss V-pass -> resp s[36][37] (r -> y = by-2+r); -INF outside image
    for (int e = tid; e < 36*36; e += 256) {
      int rr2 = e/36, c = e%36;
      int X = bx - 2 + c, Y = by - 2 + rr2;
      float val = -INFINITY;
      if (X>=0 && X<WW && Y>=0 && Y<HH) {
        float axx = 0.f, ayy = 0.f, axy = 0.f;
        #pragma unroll
        for (int i = 0; i < 7; i++) {
          float Gi = Gw[i];
          int hb = (rr2+i)*36 + c;
          axx += Gi*hxx[hb]; ayy += Gi*hyy[hb]; axy += Gi*hxy[hb];
        }
        float tr = axx + ayy;
        float det = axx*ayy - axy*axy;
        float disc = fmaxf(tr*tr - 4.0f*det, 0.f);
        val = 0.5f*(tr - sqrtf(disc));
      }
      s[rr2*37 + c] = val;
    }
    __syncthreads();
    // phase 5: NMS horizontal max -> hm[36][32]
    for (int e = tid; e < 36*32; e += 256) {
      int rr2 = e >> 5, co = e & 31;
      int base = rr2*37 + co;
      float m = s[base];
      m = fmaxf(m, s[base+1]); m = fmaxf(m, s[base+2]);
      m = fmaxf(m, s[base+3]); m = fmaxf(m, s[base+4]);
      hm[e] = m;
    }
    __syncthreads();
    // phase 6: NMS vertical + c32 + zero scatter target
    for (int e = tid; e < 1024; e += 256) {
      int y = e >> 5, x = e & 31;
      float mp = hm[y*32+x];
      mp = fmaxf(mp, hm[(y+1)*32+x]); mp = fmaxf(mp, hm[(y+2)*32+x]);
      mp = fmaxf(mp, hm[(y+3)*32+x]); mp = fmaxf(mp, hm[(y+4)*32+x]);
      float v = s[(y+2)*37 + (x+2)];
      c32[e] = (v == mp) ? v : 0.f;
      target[(size_t)b*HWSZ + (by+y)*WW + (bx+x)] = 0.f;
    }
    __syncthreads();
    // phase 7: per-8x8-block candidate extraction
    int wv = tid >> 6, lane = tid & 63;
    int ly8 = lane >> 3, lx8 = lane & 7;
    for (int q = 0; q < 4; q++) {
      int bb = wv*4 + q;
      int oy = (bb >> 2)*8, ox = (bb & 3)*8;
      float cval = c32[(oy+ly8)*32 + ox+lx8];
      float bm = wredmaxf(cval);
      bool win = (cval > 0.f) && (cval == bm);
      unsigned long long mask = __ballot(win);
      int BY = byi*4 + (bb >> 2), BX = bxi*4 + (bb & 3);
      int rblk = BY*80 + BX;
      int gidx = (by+oy+ly8)*WW + (bx+ox+lx8);
      if (mask == 0ull) {
        if (lane == 0) { cv[b*NBLK+rblk] = 0.f; ci[b*NBLK+rblk] = 0; }
      } else if (win) {
        int rank = __popcll(mask & ((1ull << lane) - 1ull));
        if (rank == 0) { cv[b*NBLK+rblk] = cval; ci[b*NBLK+rblk] = gidx; }
        else {
          int pos = atomicAdd(&ovf[b*64], 1);
          if (pos < NOVF) { cvo[b*NOVF+pos] = cval; cio[b*NOVF+pos] = gidx; }
        }
      }
    }
  } else if (bid < 3400) {
    // desc normalize: 4 rows/block, one wave per row, float4 lanes, no barriers
    int row = (bid - 2400)*4 + (tid >> 6);
    int lane = tid & 63;
    float4 v4 = *(const float4*)&desc[(size_t)row*DDIM + lane*4];
    float sacc = v4.x*v4.x + v4.y*v4.y + v4.z*v4.z + v4.w*v4.w;
    #pragma unroll
    for (int o = 32; o > 0; o >>= 1) sacc += __shfl_down(sacc, o, 64);
    sacc = __shfl(sacc, 0, 64);
    float den = fmaxf(sqrtf(sacc), 1e-8f);
    float4 o4 = make_float4(v4.x/den, v4.y/den, v4.z/den, v4.w/den);
    *(float4*)&dn[(size_t)row*DDIM + lane*4] = o4;
    int pr = (row/500)*512 + (row%500);             // padded bf16 row
    unsigned lo = (unsigned)f2bf(o4.x) | ((unsigned)f2bf(o4.y) << 16);
    unsigned hi = (unsigned)f2bf(o4.z) | ((unsigned)f2bf(o4.w) << 16);
    *(uint2*)&dnb[(size_t)pr*DDIM + lane*4] = make_uint2(lo, hi);
  } else if (bid < 3416) {
    int t = (bid - 3400)*256 + tid;
    if (t < BB*NN) {
      int a = t / NN, m = t % NN;
      float p0 = points[t*2], p1 = points[t*2+1];
      float px = (p0 + 1.0f)*0.5f*639.0f;
      float py = (p1 + 1.0f)*0.5f*479.0f;
      float Xw[3], d;
      src_compute(px, py, depths + (size_t)a*HWSZ, poses, Km, a, Xw, &d);
      psrc[t*2] = px; psrc[t*2+1] = py;
      for (int b = 0; b < BB; b++) {
        float nx, ny; bool inv;
        project_to(poses, Km, b, Xw, d, &nx, &ny, &inv);
        int o = (a*BB + b)*NN + m;
        pdst[o*2]   = (nx + 1.0f)*0.5f*639.0f;   // raw projections (reference match path)
        pdst[o*2+1] = (ny + 1.0f)*0.5f*479.0f;
        minv[o] = inv ? 1 : 0;
      }
    }
  } else {
    int blk = bid - 3416;
    int g = blk*256 + tid;
    double l = 0.0;
    for (int q = g; q < BHW/4; q += NBCE2*256) {
      float4 v = ((const float4*)pn)[q];
      l -= (double)fmaxf(logf(1.f - v.x), -100.f);
      l -= (double)fmaxf(logf(1.f - v.y), -100.f);
      l -= (double)fmaxf(logf(1.f - v.z), -100.f);
      l -= (double)fmaxf(logf(1.f - v.w), -100.f);
    }
    double sred = blockRedSum256(l);
    if (tid == 0) pd[PD_BCE + blk] = sred;
  }
}

// top-500 radix select + fused projection scatter (per-wave privatized histograms,
// ballot-aggregated extraction). Top-500 kept entirely in LDS.
__global__ __launch_bounds__(1024) void k_topscat(const float* __restrict__ cv, const int* __restrict__ ci,
                                                  const float* __restrict__ cvo, const int* __restrict__ cio,
                                                  const int* __restrict__ ovf,
                                                  const float* __restrict__ depths, const float* __restrict__ poses,
                                                  const float* __restrict__ Km,
                                                  unsigned int* __restrict__ target, int* __restrict__ list) {
  __shared__ unsigned int hist[16*257];
  __shared__ unsigned int histsum[256];
  __shared__ unsigned long long prefix_s;
  __shared__ int kk_s, fin_s, cgt_s, ceq_s;
  __shared__ float s_topv[NN];
  __shared__ int s_topi[NN];
  int b = blockIdx.x;
  int tid = threadIdx.x;
  int w257 = (tid >> 6)*257;
  int nval = min(ovf[b*64], NOVF);
  unsigned long long kreg[8];
  #pragma unroll
  for (int q = 0; q < 8; q++) {
    int e = tid + q*1024;
    float v = 0.f; unsigned int idx = 0u;
    if (e < NBLK) { v = cv[b*NBLK+e]; idx = (unsigned int)ci[b*NBLK+e]; }
    else if (e - NBLK < nval) { v = cvo[b*NOVF+e-NBLK]; idx = (unsigned int)cio[b*NOVF+e-NBLK]; }
    kreg[q] = ((unsigned long long)__float_as_uint(v) << 32) | (0xFFFFFFFFu - idx);
  }
  if (tid == 0) { prefix_s = 0ull; kk_s = NN; fin_s = -1; cgt_s = 0; ceq_s = 0; }
  for (int e = tid; e < 16*257; e += 1024) hist[e] = 0u;
  __syncthreads();
  for (int round = 0; round < 8; round++) {
    int shift = 56 - 8*round;
    unsigned long long prefix = prefix_s;
    int kk = kk_s;
    unsigned long long himask = (round == 0) ? 0ull : (~0ull << (shift + 8));
    #pragma unroll
    for (int q = 0; q < 8; q++)
      if ((kreg[q] & himask) == prefix)
        atomicAdd(&hist[w257 + (unsigned int)((kreg[q] >> shift) & 255ull)], 1u);
    __syncthreads();
    if (tid < 256) {
      unsigned s = 0u;
      #pragma unroll
      for (int ww = 0; ww < 16; ww++) s += hist[ww*257 + tid];
      histsum[tid] = s;
    }
    __syncthreads();
    for (int e = tid; e < 16*257; e += 1024) hist[e] = 0u;
    if (tid < 64) {
      int l = tid;
      unsigned s0 = histsum[l], s1 = histsum[64+l], s2 = histsum[128+l], s3 = histsum[192+l];
      #pragma unroll
      for (int off = 1; off < 64; off <<= 1) {
        unsigned t0 = __shfl_down(s0, off, 64), t1 = __shfl_down(s1, off, 64);
        unsigned t2 = __shfl_down(s2, off, 64), t3 = __shfl_down(s3, off, 64);
        if (l + off < 64) { s0 += t0; s1 += t1; s2 += t2; s3 += t3; }
      }
      unsigned S1 = __shfl(s1, 0, 64), S2 = __shfl(s2, 0, 64), S3 = __shfl(s3, 0, 64);
      unsigned suf0 = s0 + S1 + S2 + S3, suf1 = s1 + S2 + S3, suf2 = s2 + S3, suf3 = s3;
      int best = -1;
      if      (suf3 >= (unsigned)kk) best = 192 + l;
      else if (suf2 >= (unsigned)kk) best = 128 + l;
      else if (suf1 >= (unsigned)kk) best = 64 + l;
      else if (suf0 >= (unsigned)kk) best = l;
      #pragma unroll
      for (int off = 1; off < 64; off <<= 1) best = max(best, __shfl_xor(best, off, 64));
      if (l == (best & 63)) {
        int seg = best >> 6;
        unsigned sufb = (seg == 3) ? suf3 : ((seg == 2) ? suf2 : ((seg == 1) ? suf1 : suf0));
        unsigned c = histsum[best];
        int Sn = (int)(sufb - c);
        int kkn = kk - Sn;
        prefix_s = prefix | ((unsigned long long)best << shift);
        kk_s = kkn;
        if (kkn == (int)c) fin_s = shift;
      }
    }
    __syncthreads();
    if (fin_s >= 0) break;
  }
  int sg = (fin_s > 0) ? fin_s : 0;
  unsigned long long prefix = prefix_s;
  int kk = kk_s;
  unsigned long long low = (sg > 0) ? ((1ull << sg) - 1ull) : 0ull;
  unsigned long long Tfull = prefix | low;
  unsigned long long mhi = ~low;
  int lane = tid & 63;
  unsigned long long lmask = (1ull << lane) - 1ull;
  #pragma unroll
  for (int q = 0; q < 8; q++) {
    unsigned long long key = kreg[q];
    bool gt = key > Tfull;
    bool eq = !gt && ((key & mhi) == prefix);
    unsigned long long mg = __ballot(gt);
    unsigned long long me = __ballot(eq);
    int slot = -1;
    if (mg != 0ull) {
      int ldr = __ffsll((long long)mg) - 1;
      int baseg = 0;
      if (lane == ldr) baseg = atomicAdd(&cgt_s, (int)__popcll(mg));
      baseg = __shfl(baseg, ldr, 64);
      if (gt) slot = baseg + (int)__popcll(mg & lmask);
    }
    if (me != 0ull) {
      int ldr = __ffsll((long long)me) - 1;
      int basee = 0;
      if (lane == ldr) basee = atomicAdd(&ceq_s, (int)__popcll(me));
      basee = __shfl(basee, ldr, 64);
      if (eq) {
        int p = basee + (int)__popcll(me & lmask);
        if (p < kk) slot = (NN-1) - p;
      }
    }
    if (slot >= 0) {
      s_topv[slot] = __uint_as_float((unsigned int)(key >> 32));
      s_topi[slot] = (int)(0xFFFFFFFFu - (unsigned int)(key & 0xFFFFFFFFull));
    }
  }
  __syncthreads();
  // ---- fused scatter: this block owns image b; 500 threads project its corners
  if (tid < NN) {
    float val = s_topv[tid];
    if (val > 0.f) {
      int idx = s_topi[tid];
      float xs = (float)(idx % WW), ys = (float)(idx / WW);
      float cx = 2.0f*xs/639.0f - 1.0f;
      float cy = 2.0f*ys/479.0f - 1.0f;
      float px = (cx + 1.0f)*0.5f*639.0f;
      float py = (cy + 1.0f)*0.5f*479.0f;
      float Xw[3], d;
      src_compute(px, py, depths + (size_t)b*HWSZ, poses, Km, b, Xw, &d);
      int tglob = b*NN + tid;
      for (int j = 0; j < BB; j++) {
        float nx, ny; bool inv;
        project_to(poses, Km, j, Xw, d, &nx, &ny, &inv);
        if (inv) { nx = -2.0f; ny = -2.0f; }
        float fx = rintf((nx + 1.0f)*0.5f*639.0f);
        float fy = rintf((ny + 1.0f)*0.5f*479.0f);
        int wq = (int)fx, hq = (int)fy;
        if (wq < 0) continue;
        int hc = min(max(hq, 0), HH-1), wc = min(max(wq, 0), WW-1);
        int p = j*HWSZ + hc*WW + wc;
        unsigned int old = atomicMax(&target[p], __float_as_uint(val));
        if (old == 0u) list[tglob*BB + j] = p;   // first writer, exactly once per pixel
      }
    }
  }
}

// k_last: [0,NDM) distinction via bf16 MFMA; [NDM,NDM+512) match slices;
// [NDM+512,703) BCE correction. LAST of all 703 blocks (ticket) does the final
// reduction and writes the loss.
__global__ __launch_bounds__(256) void k_last(const float* __restrict__ psrc, const float* __restrict__ pdst,
                                              const int* __restrict__ minv, const float* __restrict__ dn,
                                              const short* __restrict__ dnb,
                                              const int* __restrict__ list, const float* __restrict__ target,
                                              const float* __restrict__ pn, double* __restrict__ pd,
                                              int* __restrict__ done, float* __restrict__ out) {
  __shared__ float sbuf[2500];
  __shared__ int lastf;
  int bid = blockIdx.x, tid = threadIdx.x;
  if (bid < NDM) {
    // ---- distinction: 16x16 lower-tri tiles via v_mfma_f32_16x16x32_bf16 (no LDS)
    int w = tid >> 6, lane = tid & 63;
    int gw = bid*4 + w;                          // 0..263
    int r16 = lane & 15, koff = (lane >> 4)*8;
    double dsum = 0.0;
    for (int j = 0; j < 16; j++) {
      int jb = gw*16 + j;                        // 0..4223
      int b = jb / 528, t = jb % 528;
      int I = (int)((sqrtf(8.f*(float)t + 1.f) - 1.f)*0.5f);
      while ((I+1)*(I+2)/2 <= t) I++;
      while (I*(I+1)/2 > t) I--;
      int J = t - I*(I+1)/2;
      const short* bp = dnb + (size_t)b*512*DDIM;
      const short* ap = bp + (I*16 + r16)*DDIM + koff;
      const short* cp = bp + (J*16 + r16)*DDIM + koff;
      f32x4 acc = {0.f, 0.f, 0.f, 0.f};
      #pragma unroll
      for (int kk = 0; kk < 8; kk++) {
        short8 af = *(const short8*)(ap + kk*32);
        short8 bf = *(const short8*)(cp + kk*32);
        acc = __builtin_amdgcn_mfma_f32_16x16x32_bf16(af, bf, acc, 0, 0, 0);
      }
      float ls = fmaxf(acc[0],0.f) + fmaxf(acc[1],0.f) + fmaxf(acc[2],0.f) + fmaxf(acc[3],0.f);
      dsum += (double)ls * ((I == J) ? 1.0 : 2.0);
    }
    double s = blockRedSum256(dsum);
    if (tid == 0) pd[PD_DIST + bid] = s;
  } else if (bid < NDM + 512) {
    // ---- match slice: mm strided by 8 (balanced), nn-inner coalesced
    int mbid = bid - NDM;              // 0..511
    float* spd = sbuf;                 // 1000
    float* ssrc = sbuf + 1000;         // 1000
    int* sinv = (int*)(sbuf + 2000);   // 500
    int ab = mbid & 63; int b = ab % BB; int a = ab / BB;
    int ys = mbid >> 6;                // 0..7 stripe
    for (int e = tid; e < NN; e += 256) {
      spd[e*2]   = pdst[(ab*NN+e)*2];
      spd[e*2+1] = pdst[(ab*NN+e)*2+1];
      sinv[e]    = minv[ab*NN+e];
      ssrc[e*2]   = psrc[(b*NN+e)*2];
      ssrc[e*2+1] = psrc[(b*NN+e)*2+1];
    }
    __syncthreads();
    double lsum = 0.0, lcnt = 0.0;
    for (int mm = ys; mm < NN; mm += 8) {
      float px = spd[mm*2], py = spd[mm*2+1];
      for (int nn = tid; nn < mm; nn += 256) {
        if (sinv[nn]) continue;        // reference quirk: invis indexed by n
        float dx = ssrc[nn*2]   - px;
        float dy = ssrc[nn*2+1] - py;
        if (dx*dx + dy*dy <= 1.0f) {
          const float* da = dn + ((size_t)a*NN + mm)*DDIM;
          const float* db = dn + ((size_t)b*NN + nn)*DDIM;
          float dot = 0.f;
          for (int q = 0; q < DDIM; q++) dot += db[q]*da[q];
          lsum += (double)(1.0f - dot);
          lcnt += 1.0;
        }
      }
    }
    double s = blockRedSum256(lsum);
    if (tid == 0) pd[PD_MS + mbid] = s;
    double c2 = blockRedSum256(lcnt);
    if (tid == 0) pd[PD_MC + mbid] = c2;
  } else {
    // ---- BCE correction at scattered pixels
    int blk = bid - (NDM + 512);
    int g = blk*256 + tid;
    double l = 0.0;
    if (g < NLIST) {
      int p = list[g];
      if (p >= 0) {
        int j = p / HWSZ, pix = p % HWSZ;
        int y = pix / WW, x = pix % WW;
        const float* tb = target + (size_t)j*HWSZ;
        float v = tb[pix];
        float mp = -INFINITY;
        for (int dy = -2; dy <= 2; dy++) {
          int yy = y + dy; if (yy < 0 || yy >= HH) continue;
          for (int dx = -2; dx <= 2; dx++) {
            int xx = x + dx; if (xx < 0 || xx >= WW) continue;
            mp = fmaxf(mp, tb[yy*WW+xx]);
          }
        }
        if (v > 0.f && v == mp) {
          float pv = pn[p];
          l = (double)(-fmaxf(logf(pv), -100.f)) + (double)fmaxf(logf(1.f - pv), -100.f);
        }
      }
    }
    double s = blockRedSum256(l);
    if (tid == 0) pd[PD_CORR + blk] = s;
  }
  // ---- ticket: last of 703 blocks reduces everything and writes the loss
  if (tid == 0) {
    __threadfence();
    int t = atomicAdd(done, 1);
    lastf = (t == NLAST - 1) ? 1 : 0;
  }
  __syncthreads();
  if (lastf) {
    __threadfence();
    double l2;
    l2 = 0.0; for (int i = tid; i < NDM;   i += 256) l2 += pd[PD_DIST + i];
    double dist = blockRedSum256(l2);
    l2 = 0.0; for (int i = tid; i < 512;   i += 256) l2 += pd[PD_MS + i];
    double ms = blockRedSum256(l2);
    l2 = 0.0; for (int i = tid; i < 512;   i += 256) l2 += pd[PD_MC + i];
    double mc = blockRedSum256(l2);
    l2 = 0.0; for (int i = tid; i < NBCE2; i += 256) l2 += pd[PD_BCE + i];
    double bce = blockRedSum256(l2);
    l2 = 0.0; for (int i = tid; i < NCORR; i += 256) l2 += pd[PD_CORR + i];
    double corr = blockRedSum256(l2);
    if (tid == 0) {
      float distf = (float)(dist / (double)(BB*NN*NN));
      float cornf = (float)((bce + corr) / (double)BHW);
      float cntf  = fmaxf((float)mc, 1.0f);
      float matchf = (float)ms / cntf;
      out[0] = distf + cornf + matchf;
    }
  }
}

// ---------------- host ----------------

extern "C" void kernel_launch(void* const* d_in, const int* in_sizes, int n_in,
                              void* d_out, int out_size, void* d_ws, size_t ws_size,
                              hipStream_t stream) {
  (void)in_sizes; (void)n_in; (void)out_size; (void)ws_size;
  const float* desc      = (const float*)d_in[0];
  const float* points    = (const float*)d_in[1];
  const float* pointness = (const float*)d_in[2];
  const float* depths    = (const float*)d_in[3];
  const float* poses     = (const float*)d_in[4];
  const float* Kmat      = (const float*)d_in[5];
  const float* imgs      = (const float*)d_in[6];
  float* out = (float*)d_out;

  double* pd = (double*)d_ws;                      // partial sums first (8B aligned)
  float* f = (float*)(pd + PD_TOTAL);
  float* bufC = f;                                 // scatter target
  float* cv_main = bufC + (size_t)BHW;             // 8 x 4800
  int*   ci_main = (int*)(cv_main + BB*NBLK);
  float* cv_ovf  = (float*)(ci_main + BB*NBLK);    // 8 x 3392 (stale-safe: count-masked)
  int*   ci_ovf  = (int*)(cv_ovf + BB*NOVF);
  int*   ovf     = (int*)(ci_ovf + BB*NOVF);       // 8 x stride-64 counters (init in k_front)
  float* psrc = (float*)(ovf + BB*64);
  float* pdst = psrc + BB*NN*2;
  int*   minv = (int*)(pdst + BB*BB*NN*2);
  float* dn   = (float*)(minv + BB*BB*NN);         // 8*500*256 floats
  int*   list = (int*)(dn + (size_t)BB*NN*DDIM);   // 32000 ints (init in k_front)
  unsigned short* dnb = (unsigned short*)(list + NLIST);  // 8*512*256 bf16 (pad init in k_front)
  int*   done = (int*)(dnb + (size_t)BB*512*DDIM); // ticket counter (zeroed in k_front)

  k_front  <<<3928, 256, 0, stream>>>(imgs, cv_main, ci_main, cv_ovf, ci_ovf, ovf, list,
                                      (unsigned int*)dnb, done, desc, dn, dnb,
                                      points, depths, poses, Kmat,
                                      psrc, pdst, minv, pointness, pd, bufC);
  k_topscat<<<BB, 1024, 0, stream>>>(cv_main, ci_main, cv_ovf, ci_ovf, ovf,
                                     depths, poses, Kmat, (unsigned int*)bufC, list);
  k_last   <<<NLAST, 256, 0, stream>>>(psrc, pdst, minv, dn, (const short*)dnb,
                                       list, bufC, pointness, pd, done, out);
}

// Round 16
// 106.885 us; speedup vs baseline: 1.1070x; 1.1070x over previous
//
#include <hip/hip_runtime.h>
#include <math.h>

#define BB 8
#define NN 500
#define DDIM 256
#define HH 480
#define WW 640
#define HWSZ (HH*WW)        // 307200
#define BHW (BB*HWSZ)       // 2457600
#define NBLK 4800           // 8x8 blocks per image
#define NOVF 3392           // overflow candidate slots per image
#define NLIST (BB*NN*BB)    // 32000 deterministic list slots
#define NBCE2 512           // bce streaming blocks (inside k_front)
#define NCORR 125           // ceil(32000/256)
#define NDM 132             // dist-mfma blocks: 132*4 waves * 8 jobs = 4224 = 8*528 tiles

// partial-sum slot map (doubles at ws start)
#define PD_DIST  0          // 132 used
#define PD_MS    512        // 512
#define PD_MC    1024       // 512
#define PD_BCE   1536       // 512
#define PD_CORR  2560       // 125
#define PD_TOTAL 2688

typedef __attribute__((ext_vector_type(8))) short short8;
typedef __attribute__((ext_vector_type(4))) float f32x4;

// ---------------- helpers ----------------

static __device__ __forceinline__ float wredmaxf(float v) {
  #pragma unroll
  for (int o = 1; o < 64; o <<= 1) v = fmaxf(v, __shfl_xor(v, o, 64));
  return v;
}

static __device__ __forceinline__ double blockRedSum256(double v) {
  __shared__ double sp[4];
  __syncthreads();
  #pragma unroll
  for (int o = 32; o > 0; o >>= 1) v += __shfl_down(v, o, 64);
  int lane = threadIdx.x & 63, wid = threadIdx.x >> 6;
  if (lane == 0) sp[wid] = v;
  __syncthreads();
  double r = 0.0;
  if (threadIdx.x == 0) r = sp[0] + sp[1] + sp[2] + sp[3];
  return r;
}

static __device__ __forceinline__ unsigned short f2bf(float f) {
  unsigned u = __float_as_uint(f);
  return (unsigned short)((u + 0x7FFFu + ((u >> 16) & 1u)) >> 16);   // RNE
}

static __device__ __forceinline__ float bilin(const float* __restrict__ img, float px, float py) {
  float x = fminf(fmaxf(px, 0.0f), 639.0f);
  float y = fminf(fmaxf(py, 0.0f), 479.0f);
  float x0 = floorf(x), y0 = floorf(y);
  float x1 = fminf(x0 + 1.0f, 639.0f);
  float y1 = fminf(y0 + 1.0f, 479.0f);
  float wx = x - x0, wy = y - y0;
  int x0i = (int)x0, x1i = (int)x1, y0i = (int)y0, y1i = (int)y1;
  float v00 = img[y0i*WW + x0i], v01 = img[y0i*WW + x1i];
  float v10 = img[y1i*WW + x0i], v11 = img[y1i*WW + x1i];
  return v00*(1.0f-wx)*(1.0f-wy) + v01*wx*(1.0f-wy) + v10*(1.0f-wx)*wy + v11*wx*wy;
}

// world point from pixel (px,py) in image bimg; replicates reference op order
static __device__ void src_compute(float px, float py, const float* __restrict__ dep,
                                   const float* __restrict__ poses, const float* __restrict__ Km,
                                   int bimg, float* Xw, float* dout) {
  float d = bilin(dep, px, py);
  const float* Kb = Km + bimg*9;
  double a00=Kb[0],a01=Kb[1],a02=Kb[2],a10=Kb[3],a11=Kb[4],a12=Kb[5],a20=Kb[6],a21=Kb[7],a22=Kb[8];
  double det = a00*(a11*a22-a12*a21) - a01*(a10*a22-a12*a20) + a02*(a10*a21-a11*a20);
  double id = 1.0/det;
  float i00=(float)((a11*a22-a12*a21)*id), i01=(float)((a02*a21-a01*a22)*id), i02=(float)((a01*a12-a02*a11)*id);
  float i10=(float)((a12*a20-a10*a22)*id), i11=(float)((a00*a22-a02*a20)*id), i12=(float)((a02*a10-a00*a12)*id);
  float i20=(float)((a10*a21-a11*a20)*id), i21=(float)((a01*a20-a00*a21)*id), i22=(float)((a00*a11-a01*a10)*id);
  float c0 = i00*px + i01*py + i02;
  float c1 = i10*px + i11*py + i12;
  float c2 = i20*px + i21*py + i22;
  float X0 = d*c0, X1 = d*c1, X2 = d*c2;
  const float* P = poses + bimg*16;
  Xw[0] = (P[0]*X0 + P[1]*X1 + P[2]*X2)  + P[3];
  Xw[1] = (P[4]*X0 + P[5]*X1 + P[6]*X2)  + P[7];
  Xw[2] = (P[8]*X0 + P[9]*X1 + P[10]*X2) + P[11];
  *dout = d;
}

static __device__ void project_to(const float* __restrict__ poses, const float* __restrict__ Km,
                                  int j, const float* Xw, float dsrc,
                                  float* pnx, float* pny, bool* invis) {
  const float* P = poses + j*16;
  float d0 = Xw[0]-P[3], d1 = Xw[1]-P[7], d2 = Xw[2]-P[11];
  float Xj0 = P[0]*d0 + P[4]*d1 + P[8]*d2;
  float Xj1 = P[1]*d0 + P[5]*d1 + P[9]*d2;
  float Xj2 = P[2]*d0 + P[6]*d1 + P[10]*d2;
  const float* Kb = Km + j*9;
  float u = Kb[0]*Xj0 + Kb[1]*Xj1 + Kb[2]*Xj2;
  float v = Kb[3]*Xj0 + Kb[4]*Xj1 + Kb[5]*Xj2;
  float z = Kb[6]*Xj0 + Kb[7]*Xj1 + Kb[8]*Xj2;
  float zs = (fabsf(z) < 1e-6f) ? 1e-6f : z;
  float pu = u/zs, pv = v/zs;
  float nx = 2.0f*pu/639.0f - 1.0f;
  float ny = 2.0f*pv/479.0f - 1.0f;
  *pnx = nx; *pny = ny;
  *invis = (z <= 1e-6f) || (fabsf(nx) > 1.0f) || (fabsf(ny) > 1.0f) || (dsrc <= 0.0f);
}

// ---------------- kernels ----------------

// k_front: [0,2400) fused gray->sobel->separable-GFTT tiles (+ ws inits on bid<20);
// [2400,3400) desc normalize (4 rows/block, wave-per-row); [3400,3416) match src+proj;
// [3416,3928) streaming BCE (t=false assumption).
__global__ __launch_bounds__(256) void k_front(const float* __restrict__ imgs, float* __restrict__ resp,
                                               int* __restrict__ ovf, int* __restrict__ list,
                                               unsigned int* __restrict__ dnb_u, int* __restrict__ done,
                                               const float* __restrict__ desc, float* __restrict__ dn,
                                               unsigned short* __restrict__ dnb,
                                               const float* __restrict__ points, const float* __restrict__ depths,
                                               const float* __restrict__ poses, const float* __restrict__ Km,
                                               float* __restrict__ psrc, float* __restrict__ pdst,
                                               int* __restrict__ minv,
                                               const float* __restrict__ pn, double* __restrict__ pd) {
  __shared__ float smem[6536];
  __shared__ float Gw[7];
  int bid = blockIdx.x, tid = threadIdx.x;
  if (bid < 2400) {
    float* sgxy = smem;              // [38][38][2] interleaved gx,gy
    float* gray = smem + 2888;       // [40][41]  (dead after sobel)
    float* hxx  = smem + 2888;       // [38][32] aliases gray
    float* hyy  = hxx + 1216;
    float* hxy  = hyy + 1216;
    int b = bid / 300, r = bid % 300;
    int byi = r / 20, bxi = r % 20;
    int bx = bxi*32, by = byi*32;
    int tx = tid & 31, ty = tid >> 5;
    if (bid < 20) {
      int g = bid*256 + tid;                 // 0..5119
      if (g == 0) *done = 0;
      for (int e = g; e < BB*64; e += 20*256) ovf[e] = 0;
      for (int e = g; e < NLIST; e += 20*256) list[e] = -1;
      for (int e = g; e < 12288; e += 20*256) {     // zero bf16 pad rows 500..511 per image
        int bi = e / 1536, rr2 = e % 1536;
        dnb_u[(bi*512 + 500)*128 + rr2] = 0u;
      }
    }
    if (tid < 7) {
      double g[7]; double s = 0.0;
      for (int q = 0; q < 7; q++) { double rr2 = (double)(q-3); g[q] = exp(-(rr2*rr2)/2.0); s += g[q]; }
      Gw[tid] = (float)(g[tid]/s);
    }
    const float* ib = imgs + (size_t)b*3*HWSZ;
    for (int ly = ty; ly < 40; ly += 8) {
      int Y = by - 4 + ly;
      bool yin = (Y >= 0 && Y < HH);
      for (int lx = tx; lx < 40; lx += 32) {
        int X = bx - 4 + lx;
        float v = 0.f;
        if (yin && X >= 0 && X < WW) {
          int p = Y*WW + X;
          v = 0.299f*ib[p] + 0.587f*ib[HWSZ+p] + 0.114f*ib[2*HWSZ+p];
        }
        gray[ly*41+lx] = v;
      }
    }
    __syncthreads();
    const float kxw[3][3] = {{-0.125f,0.f,0.125f},{-0.25f,0.f,0.25f},{-0.125f,0.f,0.125f}};
    for (int ly = ty; ly < 38; ly += 8) {
      int Y = by - 3 + ly;
      bool yin = (Y >= 0 && Y < HH);
      for (int lx = tx; lx < 38; lx += 32) {
        int X = bx - 3 + lx;
        float sx = 0.f, sy = 0.f;
        #pragma unroll
        for (int i = 0; i < 3; i++)
          #pragma unroll
          for (int j = 0; j < 3; j++) {
            float v = gray[(ly+i)*41 + (lx+j)];
            sx += kxw[i][j]*v;
            sy += kxw[j][i]*v;
          }
        bool in = yin && (X >= 0 && X < WW);
        int e = ly*38 + lx;
        sgxy[e*2]   = in ? sx : 0.f;    // conv zero-pad semantics
        sgxy[e*2+1] = in ? sy : 0.f;
      }
    }
    __syncthreads();
    for (int rr2 = ty; rr2 < 38; rr2 += 8) {
      int base = (rr2*38 + tx)*2;
      float axx = 0.f, ayy = 0.f, axy = 0.f;
      #pragma unroll
      for (int j = 0; j < 7; j++) {
        float a = sgxy[base + j*2];
        float c = sgxy[base + j*2 + 1];
        float Gj = Gw[j];
        axx += Gj*(a*a); ayy += Gj*(c*c); axy += Gj*(a*c);
      }
      int e = rr2*32 + tx;
      hxx[e] = axx; hyy[e] = ayy; hxy[e] = axy;
    }
    __syncthreads();
    int r0 = ty*4;
    float axx[4] = {0,0,0,0}, ayy[4] = {0,0,0,0}, axy[4] = {0,0,0,0};
    #pragma unroll
    for (int rr2 = 0; rr2 < 10; rr2++) {
      int rr3 = r0 + rr2;
      float vxx = hxx[rr3*32+tx], vyy = hyy[rr3*32+tx], vxy = hxy[rr3*32+tx];
      #pragma unroll
      for (int o = 0; o < 4; o++) {
        int i = rr2 - o;
        if (i >= 0 && i <= 6) {
          float Gi = Gw[i];
          axx[o] += Gi*vxx; ayy[o] += Gi*vyy; axy[o] += Gi*vxy;
        }
      }
    }
    #pragma unroll
    for (int o = 0; o < 4; o++) {
      float tr = axx[o] + ayy[o];
      float det = axx[o]*ayy[o] - axy[o]*axy[o];
      float disc = fmaxf(tr*tr - 4.0f*det, 0.f);
      int y = by + r0 + o;
      resp[(size_t)b*HWSZ + y*WW + (bx+tx)] = 0.5f*(tr - sqrtf(disc));
    }
  } else if (bid < 3400) {
    // desc normalize: 4 rows/block, one wave per row, float4 lanes, no barriers
    int row = (bid - 2400)*4 + (tid >> 6);
    int lane = tid & 63;
    float4 v4 = *(const float4*)&desc[(size_t)row*DDIM + lane*4];
    float s = v4.x*v4.x + v4.y*v4.y + v4.z*v4.z + v4.w*v4.w;
    #pragma unroll
    for (int o = 32; o > 0; o >>= 1) s += __shfl_down(s, o, 64);
    s = __shfl(s, 0, 64);
    float den = fmaxf(sqrtf(s), 1e-8f);
    float4 o4 = make_float4(v4.x/den, v4.y/den, v4.z/den, v4.w/den);
    *(float4*)&dn[(size_t)row*DDIM + lane*4] = o4;
    int pr = (row/500)*512 + (row%500);             // padded bf16 row
    unsigned lo = (unsigned)f2bf(o4.x) | ((unsigned)f2bf(o4.y) << 16);
    unsigned hi = (unsigned)f2bf(o4.z) | ((unsigned)f2bf(o4.w) << 16);
    *(uint2*)&dnb[(size_t)pr*DDIM + lane*4] = make_uint2(lo, hi);
  } else if (bid < 3416) {
    int t = (bid - 3400)*256 + tid;
    if (t < BB*NN) {
      int a = t / NN, m = t % NN;
      float p0 = points[t*2], p1 = points[t*2+1];
      float px = (p0 + 1.0f)*0.5f*639.0f;
      float py = (p1 + 1.0f)*0.5f*479.0f;
      float Xw[3], d;
      src_compute(px, py, depths + (size_t)a*HWSZ, poses, Km, a, Xw, &d);
      psrc[t*2] = px; psrc[t*2+1] = py;
      for (int b = 0; b < BB; b++) {
        float nx, ny; bool inv;
        project_to(poses, Km, b, Xw, d, &nx, &ny, &inv);
        int o = (a*BB + b)*NN + m;
        pdst[o*2]   = (nx + 1.0f)*0.5f*639.0f;   // raw projections (reference match path)
        pdst[o*2+1] = (ny + 1.0f)*0.5f*479.0f;
        minv[o] = inv ? 1 : 0;
      }
    }
  } else {
    int blk = bid - 3416;
    int g = blk*256 + tid;
    double l = 0.0;
    for (int q = g; q < BHW/4; q += NBCE2*256) {
      float4 v = ((const float4*)pn)[q];
      l -= (double)fmaxf(logf(1.f - v.x), -100.f);
      l -= (double)fmaxf(logf(1.f - v.y), -100.f);
      l -= (double)fmaxf(logf(1.f - v.z), -100.f);
      l -= (double)fmaxf(logf(1.f - v.w), -100.f);
    }
    double s = blockRedSum256(l);
    if (tid == 0) pd[PD_BCE + blk] = s;
  }
}

// k_mid: [0,NDM) distinction via bf16 MFMA (2-job ILP, 8 jobs/wave);
// [NDM,NDM+512) match slices; [NDM+512,NDM+512+2400) separable 5x5 NMS +
// candidate extraction (+ zero target). dist/match overlap the NMS tiles here.
__global__ __launch_bounds__(256) void k_mid(const float* __restrict__ resp, float* __restrict__ cv,
                                             int* __restrict__ ci, float* __restrict__ cvo,
                                             int* __restrict__ cio, int* __restrict__ ovf,
                                             float* __restrict__ target,
                                             const float* __restrict__ psrc, const float* __restrict__ pdst,
                                             const int* __restrict__ minv, const float* __restrict__ dn,
                                             const short* __restrict__ dnb, double* __restrict__ pd) {
  __shared__ float sbuf[3508];
  int bid = blockIdx.x, tid = threadIdx.x;
  if (bid < NDM) {
    // ---- distinction: 16x16 lower-tri tiles via MFMA, 2 jobs in flight (ILP)
    int w = tid >> 6, lane = tid & 63;
    int gw = bid*4 + w;                          // 0..527
    int r16 = lane & 15, koff = (lane >> 4)*8;
    double dsum = 0.0;
    #pragma unroll
    for (int jp = 0; jp < 8; jp += 2) {
      int jb0 = gw*8 + jp, jb1 = jb0 + 1;        // 0..4223
      int b0 = jb0 / 528, t0 = jb0 % 528;
      int b1 = jb1 / 528, t1 = jb1 % 528;
      int I0 = (int)((sqrtf(8.f*(float)t0 + 1.f) - 1.f)*0.5f);
      while ((I0+1)*(I0+2)/2 <= t0) I0++;
      while (I0*(I0+1)/2 > t0) I0--;
      int J0 = t0 - I0*(I0+1)/2;
      int I1 = (int)((sqrtf(8.f*(float)t1 + 1.f) - 1.f)*0.5f);
      while ((I1+1)*(I1+2)/2 <= t1) I1++;
      while (I1*(I1+1)/2 > t1) I1--;
      int J1 = t1 - I1*(I1+1)/2;
      const short* bp0 = dnb + (size_t)b0*512*DDIM;
      const short* ap0 = bp0 + (I0*16 + r16)*DDIM + koff;
      const short* cp0 = bp0 + (J0*16 + r16)*DDIM + koff;
      const short* bp1 = dnb + (size_t)b1*512*DDIM;
      const short* ap1 = bp1 + (I1*16 + r16)*DDIM + koff;
      const short* cp1 = bp1 + (J1*16 + r16)*DDIM + koff;
      f32x4 acc0 = {0.f, 0.f, 0.f, 0.f};
      f32x4 acc1 = {0.f, 0.f, 0.f, 0.f};
      #pragma unroll
      for (int kk = 0; kk < 8; kk++) {
        short8 a0 = *(const short8*)(ap0 + kk*32);
        short8 c0 = *(const short8*)(cp0 + kk*32);
        short8 a1 = *(const short8*)(ap1 + kk*32);
        short8 c1 = *(const short8*)(cp1 + kk*32);
        acc0 = __builtin_amdgcn_mfma_f32_16x16x32_bf16(a0, c0, acc0, 0, 0, 0);
        acc1 = __builtin_amdgcn_mfma_f32_16x16x32_bf16(a1, c1, acc1, 0, 0, 0);
      }
      float ls0 = fmaxf(acc0[0],0.f) + fmaxf(acc0[1],0.f) + fmaxf(acc0[2],0.f) + fmaxf(acc0[3],0.f);
      float ls1 = fmaxf(acc1[0],0.f) + fmaxf(acc1[1],0.f) + fmaxf(acc1[2],0.f) + fmaxf(acc1[3],0.f);
      dsum += (double)ls0 * ((I0 == J0) ? 1.0 : 2.0);
      dsum += (double)ls1 * ((I1 == J1) ? 1.0 : 2.0);
    }
    double s = blockRedSum256(dsum);
    if (tid == 0) pd[PD_DIST + bid] = s;
  } else if (bid < NDM + 512) {
    // ---- match slice: mm strided by 8 (balanced), nn-inner coalesced, no int div
    int mbid = bid - NDM;              // 0..511
    float* spd = sbuf;                 // 1000
    float* ssrc = sbuf + 1000;         // 1000
    int* sinv = (int*)(sbuf + 2000);   // 500
    int ab = mbid & 63; int b = ab % BB; int a = ab / BB;
    int ys = mbid >> 6;                // 0..7 stripe
    for (int e = tid; e < NN; e += 256) {
      spd[e*2]   = pdst[(ab*NN+e)*2];
      spd[e*2+1] = pdst[(ab*NN+e)*2+1];
      sinv[e]    = minv[ab*NN+e];
      ssrc[e*2]   = psrc[(b*NN+e)*2];
      ssrc[e*2+1] = psrc[(b*NN+e)*2+1];
    }
    __syncthreads();
    double lsum = 0.0, lcnt = 0.0;
    for (int mm = ys; mm < NN; mm += 8) {
      float px = spd[mm*2], py = spd[mm*2+1];
      for (int nn = tid; nn < mm; nn += 256) {
        if (sinv[nn]) continue;        // reference quirk: invis indexed by n
        float dx = ssrc[nn*2]   - px;
        float dy = ssrc[nn*2+1] - py;
        if (dx*dx + dy*dy <= 1.0f) {
          const float* da = dn + ((size_t)a*NN + mm)*DDIM;
          const float* db = dn + ((size_t)b*NN + nn)*DDIM;
          float dot = 0.f;
          for (int q = 0; q < DDIM; q++) dot += db[q]*da[q];
          lsum += (double)(1.0f - dot);
          lcnt += 1.0;
        }
      }
    }
    double s = blockRedSum256(lsum);
    if (tid == 0) pd[PD_MS + mbid] = s;
    double c2 = blockRedSum256(lcnt);
    if (tid == 0) pd[PD_MC + mbid] = c2;
  } else {
    // ---- separable 5x5 NMS + per-8x8-block candidates (+ zero scatter target)
    int nb = bid - (NDM + 512);        // 0..2399
    int b = nb / 300, r = nb % 300;
    int byi = r / 20, bxi = r % 20;
    int bx = bxi*32, by = byi*32;
    float* s = sbuf;                   // [36][37] = 1332
    float* hm = sbuf + 1332;           // [36][32] = 1152
    float* c32 = sbuf + 2484;          // [32][32] = 1024
    const float* rp = resp + (size_t)b*HWSZ;
    for (int e = tid; e < 36*36; e += 256) {
      int ly = e/36, lx = e%36;
      int X = bx - 2 + lx, Y = by - 2 + ly;
      s[ly*37+lx] = (X>=0 && X<WW && Y>=0 && Y<HH) ? rp[Y*WW+X] : -INFINITY;
    }
    __syncthreads();
    for (int e = tid; e < 36*32; e += 256) {
      int rr = e >> 5, co = e & 31;
      int base = rr*37 + co;
      float m = s[base];
      m = fmaxf(m, s[base+1]); m = fmaxf(m, s[base+2]);
      m = fmaxf(m, s[base+3]); m = fmaxf(m, s[base+4]);
      hm[e] = m;
    }
    __syncthreads();
    for (int e = tid; e < 1024; e += 256) {
      int y = e >> 5, x = e & 31;
      float mp = hm[y*32+x];
      mp = fmaxf(mp, hm[(y+1)*32+x]); mp = fmaxf(mp, hm[(y+2)*32+x]);
      mp = fmaxf(mp, hm[(y+3)*32+x]); mp = fmaxf(mp, hm[(y+4)*32+x]);
      float v = s[(y+2)*37 + (x+2)];
      c32[e] = (v == mp) ? v : 0.f;
      target[(size_t)b*HWSZ + (by+y)*WW + (bx+x)] = 0.f;
    }
    __syncthreads();
    int wv = tid >> 6, lane = tid & 63;
    int ly8 = lane >> 3, lx8 = lane & 7;
    for (int q = 0; q < 4; q++) {
      int bb = wv*4 + q;
      int oy = (bb >> 2)*8, ox = (bb & 3)*8;
      float cval = c32[(oy+ly8)*32 + ox+lx8];
      float bm = wredmaxf(cval);
      bool win = (cval > 0.f) && (cval == bm);
      unsigned long long mask = __ballot(win);
      int BY = byi*4 + (bb >> 2), BX = bxi*4 + (bb & 3);
      int rblk = BY*80 + BX;
      int gidx = (by+oy+ly8)*WW + (bx+ox+lx8);
      if (mask == 0ull) {
        if (lane == 0) { cv[b*NBLK+rblk] = 0.f; ci[b*NBLK+rblk] = 0; }
      } else if (win) {
        int rank = __popcll(mask & ((1ull << lane) - 1ull));
        if (rank == 0) { cv[b*NBLK+rblk] = cval; ci[b*NBLK+rblk] = gidx; }
        else {
          int pos = atomicAdd(&ovf[b*64], 1);
          if (pos < NOVF) { cvo[b*NOVF+pos] = cval; cio[b*NOVF+pos] = gidx; }
        }
      }
    }
  }
}

// top-500 radix select + fused projection scatter (per-wave privatized histograms,
// ballot-aggregated extraction). Top-500 kept entirely in LDS.
__global__ __launch_bounds__(1024) void k_topscat(const float* __restrict__ cv, const int* __restrict__ ci,
                                                  const float* __restrict__ cvo, const int* __restrict__ cio,
                                                  const int* __restrict__ ovf,
                                                  const float* __restrict__ depths, const float* __restrict__ poses,
                                                  const float* __restrict__ Km,
                                                  unsigned int* __restrict__ target, int* __restrict__ list) {
  __shared__ unsigned int hist[16*257];
  __shared__ unsigned int histsum[256];
  __shared__ unsigned long long prefix_s;
  __shared__ int kk_s, fin_s, cgt_s, ceq_s;
  __shared__ float s_topv[NN];
  __shared__ int s_topi[NN];
  int b = blockIdx.x;
  int tid = threadIdx.x;
  int w257 = (tid >> 6)*257;
  int nval = min(ovf[b*64], NOVF);
  unsigned long long kreg[8];
  #pragma unroll
  for (int q = 0; q < 8; q++) {
    int e = tid + q*1024;
    float v = 0.f; unsigned int idx = 0u;
    if (e < NBLK) { v = cv[b*NBLK+e]; idx = (unsigned int)ci[b*NBLK+e]; }
    else if (e - NBLK < nval) { v = cvo[b*NOVF+e-NBLK]; idx = (unsigned int)cio[b*NOVF+e-NBLK]; }
    kreg[q] = ((unsigned long long)__float_as_uint(v) << 32) | (0xFFFFFFFFu - idx);
  }
  if (tid == 0) { prefix_s = 0ull; kk_s = NN; fin_s = -1; cgt_s = 0; ceq_s = 0; }
  for (int e = tid; e < 16*257; e += 1024) hist[e] = 0u;
  __syncthreads();
  for (int round = 0; round < 8; round++) {
    int shift = 56 - 8*round;
    unsigned long long prefix = prefix_s;
    int kk = kk_s;
    unsigned long long himask = (round == 0) ? 0ull : (~0ull << (shift + 8));
    #pragma unroll
    for (int q = 0; q < 8; q++)
      if ((kreg[q] & himask) == prefix)
        atomicAdd(&hist[w257 + (unsigned int)((kreg[q] >> shift) & 255ull)], 1u);
    __syncthreads();
    if (tid < 256) {
      unsigned s = 0u;
      #pragma unroll
      for (int ww = 0; ww < 16; ww++) s += hist[ww*257 + tid];
      histsum[tid] = s;
    }
    __syncthreads();
    for (int e = tid; e < 16*257; e += 1024) hist[e] = 0u;
    if (tid < 64) {
      int l = tid;
      unsigned s0 = histsum[l], s1 = histsum[64+l], s2 = histsum[128+l], s3 = histsum[192+l];
      #pragma unroll
      for (int off = 1; off < 64; off <<= 1) {
        unsigned t0 = __shfl_down(s0, off, 64), t1 = __shfl_down(s1, off, 64);
        unsigned t2 = __shfl_down(s2, off, 64), t3 = __shfl_down(s3, off, 64);
        if (l + off < 64) { s0 += t0; s1 += t1; s2 += t2; s3 += t3; }
      }
      unsigned S1 = __shfl(s1, 0, 64), S2 = __shfl(s2, 0, 64), S3 = __shfl(s3, 0, 64);
      unsigned suf0 = s0 + S1 + S2 + S3, suf1 = s1 + S2 + S3, suf2 = s2 + S3, suf3 = s3;
      int best = -1;
      if      (suf3 >= (unsigned)kk) best = 192 + l;
      else if (suf2 >= (unsigned)kk) best = 128 + l;
      else if (suf1 >= (unsigned)kk) best = 64 + l;
      else if (suf0 >= (unsigned)kk) best = l;
      #pragma unroll
      for (int off = 1; off < 64; off <<= 1) best = max(best, __shfl_xor(best, off, 64));
      if (l == (best & 63)) {
        int seg = best >> 6;
        unsigned sufb = (seg == 3) ? suf3 : ((seg == 2) ? suf2 : ((seg == 1) ? suf1 : suf0));
        unsigned c = histsum[best];
        int Sn = (int)(sufb - c);
        int kkn = kk - Sn;
        prefix_s = prefix | ((unsigned long long)best << shift);
        kk_s = kkn;
        if (kkn == (int)c) fin_s = shift;
      }
    }
    __syncthreads();
    if (fin_s >= 0) break;
  }
  int sg = (fin_s > 0) ? fin_s : 0;
  unsigned long long prefix = prefix_s;
  int kk = kk_s;
  unsigned long long low = (sg > 0) ? ((1ull << sg) - 1ull) : 0ull;
  unsigned long long Tfull = prefix | low;
  unsigned long long mhi = ~low;
  int lane = tid & 63;
  unsigned long long lmask = (1ull << lane) - 1ull;
  #pragma unroll
  for (int q = 0; q < 8; q++) {
    unsigned long long key = kreg[q];
    bool gt = key > Tfull;
    bool eq = !gt && ((key & mhi) == prefix);
    unsigned long long mg = __ballot(gt);
    unsigned long long me = __ballot(eq);
    int slot = -1;
    if (mg != 0ull) {
      int ldr = __ffsll((long long)mg) - 1;
      int baseg = 0;
      if (lane == ldr) baseg = atomicAdd(&cgt_s, (int)__popcll(mg));
      baseg = __shfl(baseg, ldr, 64);
      if (gt) slot = baseg + (int)__popcll(mg & lmask);
    }
    if (me != 0ull) {
      int ldr = __ffsll((long long)me) - 1;
      int basee = 0;
      if (lane == ldr) basee = atomicAdd(&ceq_s, (int)__popcll(me));
      basee = __shfl(basee, ldr, 64);
      if (eq) {
        int p = basee + (int)__popcll(me & lmask);
        if (p < kk) slot = (NN-1) - p;
      }
    }
    if (slot >= 0) {
      s_topv[slot] = __uint_as_float((unsigned int)(key >> 32));
      s_topi[slot] = (int)(0xFFFFFFFFu - (unsigned int)(key & 0xFFFFFFFFull));
    }
  }
  __syncthreads();
  // ---- fused scatter: this block owns image b; 500 threads project its corners
  if (tid < NN) {
    float val = s_topv[tid];
    if (val > 0.f) {
      int idx = s_topi[tid];
      float xs = (float)(idx % WW), ys = (float)(idx / WW);
      float cx = 2.0f*xs/639.0f - 1.0f;
      float cy = 2.0f*ys/479.0f - 1.0f;
      float px = (cx + 1.0f)*0.5f*639.0f;
      float py = (cy + 1.0f)*0.5f*479.0f;
      float Xw[3], d;
      src_compute(px, py, depths + (size_t)b*HWSZ, poses, Km, b, Xw, &d);
      int tglob = b*NN + tid;
      for (int j = 0; j < BB; j++) {
        float nx, ny; bool inv;
        project_to(poses, Km, j, Xw, d, &nx, &ny, &inv);
        if (inv) { nx = -2.0f; ny = -2.0f; }
        float fx = rintf((nx + 1.0f)*0.5f*639.0f);
        float fy = rintf((ny + 1.0f)*0.5f*479.0f);
        int wq = (int)fx, hq = (int)fy;
        if (wq < 0) continue;
        int hc = min(max(hq, 0), HH-1), wc = min(max(wq, 0), WW-1);
        int p = j*HWSZ + hc*WW + wc;
        unsigned int old = atomicMax(&target[p], __float_as_uint(val));
        if (old == 0u) list[tglob*BB + j] = p;   // first writer, exactly once per pixel
      }
    }
  }
}

// k_last: BCE correction at scattered pixels; LAST block (ticket) also does the
// final reduction and writes the loss.
__global__ __launch_bounds__(256) void k_last(const int* __restrict__ list, const float* __restrict__ target,
                                              const float* __restrict__ pn, double* __restrict__ pd,
                                              int* __restrict__ done, float* __restrict__ out) {
  __shared__ int lastf;
  int blk = blockIdx.x, tid = threadIdx.x;
  int g = blk*256 + tid;
  double l = 0.0;
  if (g < NLIST) {
    int p = list[g];
    if (p >= 0) {
      int j = p / HWSZ, pix = p % HWSZ;
      int y = pix / WW, x = pix % WW;
      const float* tb = target + (size_t)j*HWSZ;
      float v = tb[pix];
      float mp = -INFINITY;
      for (int dy = -2; dy <= 2; dy++) {
        int yy = y + dy; if (yy < 0 || yy >= HH) continue;
        for (int dx = -2; dx <= 2; dx++) {
          int xx = x + dx; if (xx < 0 || xx >= WW) continue;
          mp = fmaxf(mp, tb[yy*WW+xx]);
        }
      }
      if (v > 0.f && v == mp) {
        float pv = pn[p];
        l = (double)(-fmaxf(logf(pv), -100.f)) + (double)fmaxf(logf(1.f - pv), -100.f);
      }
    }
  }
  double s = blockRedSum256(l);
  if (tid == 0) {
    pd[PD_CORR + blk] = s;
    __threadfence();
    int t = atomicAdd(done, 1);
    lastf = (t == NCORR - 1) ? 1 : 0;
  }
  __syncthreads();
  if (lastf) {
    __threadfence();
    double l2;
    l2 = 0.0; for (int i = tid; i < NDM;   i += 256) l2 += pd[PD_DIST + i];
    double dist = blockRedSum256(l2);
    l2 = 0.0; for (int i = tid; i < 512;   i += 256) l2 += pd[PD_MS + i];
    double ms = blockRedSum256(l2);
    l2 = 0.0; for (int i = tid; i < 512;   i += 256) l2 += pd[PD_MC + i];
    double mc = blockRedSum256(l2);
    l2 = 0.0; for (int i = tid; i < NBCE2; i += 256) l2 += pd[PD_BCE + i];
    double bce = blockRedSum256(l2);
    l2 = 0.0; for (int i = tid; i < NCORR; i += 256) l2 += pd[PD_CORR + i];
    double corr = blockRedSum256(l2);
    if (tid == 0) {
      float distf = (float)(dist / (double)(BB*NN*NN));
      float cornf = (float)((bce + corr) / (double)BHW);
      float cntf  = fmaxf((float)mc, 1.0f);
      float matchf = (float)ms / cntf;
      out[0] = distf + cornf + matchf;
    }
  }
}

// ---------------- host ----------------

extern "C" void kernel_launch(void* const* d_in, const int* in_sizes, int n_in,
                              void* d_out, int out_size, void* d_ws, size_t ws_size,
                              hipStream_t stream) {
  (void)in_sizes; (void)n_in; (void)out_size; (void)ws_size;
  const float* desc      = (const float*)d_in[0];
  const float* points    = (const float*)d_in[1];
  const float* pointness = (const float*)d_in[2];
  const float* depths    = (const float*)d_in[3];
  const float* poses     = (const float*)d_in[4];
  const float* Kmat      = (const float*)d_in[5];
  const float* imgs      = (const float*)d_in[6];
  float* out = (float*)d_out;

  double* pd = (double*)d_ws;                      // partial sums first (8B aligned)
  float* f = (float*)(pd + PD_TOTAL);
  float* bufA = f;                                 // resp
  float* bufC = bufA + (size_t)BHW;                // scatter target
  float* cv_main = bufC + (size_t)BHW;             // 8 x 4800
  int*   ci_main = (int*)(cv_main + BB*NBLK);
  float* cv_ovf  = (float*)(ci_main + BB*NBLK);    // 8 x 3392 (stale-safe: count-masked)
  int*   ci_ovf  = (int*)(cv_ovf + BB*NOVF);
  int*   ovf     = (int*)(ci_ovf + BB*NOVF);       // 8 x stride-64 counters (init in k_front)
  float* psrc = (float*)(ovf + BB*64);
  float* pdst = psrc + BB*NN*2;
  int*   minv = (int*)(pdst + BB*BB*NN*2);
  float* dn   = (float*)(minv + BB*BB*NN);         // 8*500*256 floats
  int*   list = (int*)(dn + (size_t)BB*NN*DDIM);   // 32000 ints (init in k_front)
  unsigned short* dnb = (unsigned short*)(list + NLIST);  // 8*512*256 bf16 (pad init in k_front)
  int*   done = (int*)(dnb + (size_t)BB*512*DDIM); // ticket counter (zeroed in k_front)

  k_front  <<<3928, 256, 0, stream>>>(imgs, bufA, ovf, list, (unsigned int*)dnb, done,
                                      desc, dn, dnb, points, depths, poses, Kmat,
                                      psrc, pdst, minv, pointness, pd);
  k_mid    <<<NDM + 512 + 2400, 256, 0, stream>>>(bufA, cv_main, ci_main, cv_ovf, ci_ovf, ovf, bufC,
                                                  psrc, pdst, minv, dn, (const short*)dnb, pd);
  k_topscat<<<BB, 1024, 0, stream>>>(cv_main, ci_main, cv_ovf, ci_ovf, ovf,
                                     depths, poses, Kmat, (unsigned int*)bufC, list);
  k_last   <<<NCORR, 256, 0, stream>>>(list, bufC, pointness, pd, done, out);
}